// Round 6
// baseline (321.997 us; speedup 1.0000x reference)
//
#include <hip/hip_runtime.h>

#define HW 16384
#define TP 72   // transposed bf16 LDS pitch (ushorts): 144B rows, 16B-aligned
                // (R2-proven layout; gemm is memory-bound, LDS conflicts hidden)

typedef unsigned short ushort_t;
typedef unsigned char uchar_t;
typedef unsigned int uint32;
typedef __attribute__((ext_vector_type(8))) short short8;
typedef __attribute__((ext_vector_type(4))) float floatx4;

__device__ __forceinline__ ushort_t f2bf(float x) {
  uint32 u = __float_as_uint(x);
  u += 0x7fffu + ((u >> 16) & 1u);
  return (ushort_t)(u >> 16);
}

// ---------------------------------------------------------------------------
// K1: binary masks, byte-packed: bit0 = erosion (AND over in-bounds 4x4
// window, SAME pad lo=1 hi=2, cv2 border semantics), bit1 = dilation (OR).
// threshold m > 0.3. 1 B/pixel (was 8 B across two float arrays).
// ---------------------------------------------------------------------------
__global__ __launch_bounds__(256) void k_masks(const float* __restrict__ m,
                                               uchar_t* __restrict__ mk) {
  int idx = blockIdx.x * 256 + threadIdx.x;   // 8*16384 total
  int b = idx >> 14;
  int p = idx & (HW - 1);
  int i = p >> 7, j = p & 127;
  const float* mb = m + (b << 14);
  float ermn = 1.f, dimx = 0.f;
  for (int di_ = -1; di_ <= 2; ++di_) {
    int ii = i + di_;
    if (ii < 0 || ii >= 128) continue;
    for (int dj = -1; dj <= 2; ++dj) {
      int jj = j + dj;
      if (jj < 0 || jj >= 128) continue;
      float z = ((double)mb[ii * 128 + jj] > 0.3) ? 1.f : 0.f;
      ermn = fminf(ermn, z);
      dimx = fmaxf(dimx, z);
    }
  }
  mk[idx] = (uchar_t)((ermn > 0.5f ? 1u : 0u) | (dimx > 0.5f ? 2u : 0u));
}

// ---------------------------------------------------------------------------
// K2: per (b,c): S_er = sum er*f, S_tot = sum f, S_di = sum di*f over HW.
// One block per (b,c); direct writes (block owns its outputs, no atomics).
// Mask is 16 KB/batch byte-packed -> L1-resident across the co-scheduled
// blocks of a batch (was 128 KB/batch of float er+di = 268 MB L2 traffic).
// ---------------------------------------------------------------------------
__global__ __launch_bounds__(256) void k_midsums(const float* __restrict__ f,
                                                 const uchar_t* __restrict__ mk,
                                                 float* __restrict__ out) {
  int b = blockIdx.x >> 8;
  int c = blockIdx.x & 255;
  const float4* f4 = (const float4*)(f + ((size_t)(b * 256 + c) << 14));
  const uint32* mk4 = (const uint32*)(mk + ((size_t)b << 14));
  int t = threadIdx.x;
  float se = 0.f, st = 0.f, sd = 0.f;
#pragma unroll
  for (int it = 0; it < 16; ++it) {
    int i = it * 256 + t;
    float4 x = f4[i];
    uint32 mm = mk4[i];   // 4 pixels: byte j -> bit(8j)=er, bit(8j+1)=di
    st += (x.x + x.y) + (x.z + x.w);
    se += (mm & 0x00000001u) ? x.x : 0.f;
    sd += (mm & 0x00000002u) ? x.x : 0.f;
    se += (mm & 0x00000100u) ? x.y : 0.f;
    sd += (mm & 0x00000200u) ? x.y : 0.f;
    se += (mm & 0x00010000u) ? x.z : 0.f;
    sd += (mm & 0x00020000u) ? x.z : 0.f;
    se += (mm & 0x01000000u) ? x.w : 0.f;
    sd += (mm & 0x02000000u) ? x.w : 0.f;
  }
  __shared__ float red[3][4];
  for (int off = 32; off; off >>= 1) {
    se += __shfl_down(se, off);
    st += __shfl_down(st, off);
    sd += __shfl_down(sd, off);
  }
  int wave = t >> 6;
  if ((t & 63) == 0) { red[0][wave] = se; red[1][wave] = st; red[2][wave] = sd; }
  __syncthreads();
  if (t == 0) {
    se = red[0][0] + red[0][1] + red[0][2] + red[0][3];
    st = red[1][0] + red[1][1] + red[1][2] + red[1][3];
    sd = red[2][0] + red[2][1] + red[2][2] + red[2][3];
    float* o = out + (size_t)(b * 256 + c) * 3;
    o[0] = se; o[1] = st; o[2] = sd;
  }
}

// ---------------------------------------------------------------------------
// K3a: per-batch small algebra, 1024 threads (4-way split of every 256-deep
// reduction loop + LDS reduce) -> Bm[3][256], A2[256][3], bias_eff.
// ---------------------------------------------------------------------------
__global__ __launch_bounds__(1024) void k_prep_a(
    const float* __restrict__ midsums, const float* __restrict__ wfeat,
    const float* __restrict__ gf, const float* __restrict__ bfp,
    const float* __restrict__ mfp, const float* __restrict__ vfp,
    const float* __restrict__ wout, const float* __restrict__ g2,
    const float* __restrict__ b2p, const float* __restrict__ m2p,
    const float* __restrict__ v2p, float* __restrict__ BmW,
    float* __restrict__ A2W, float* __restrict__ bias_eff) {
  const int b = blockIdx.x;
  const int tid = threadIdx.x;
  const int t = tid & 255;
  const int part = tid >> 8;      // 0..3
  __shared__ float mid[3][256];
  __shared__ float msc[3][256];
  __shared__ float tl[256];
  __shared__ float s2l[256], t2l[256];
  __shared__ float bias2[256];
  __shared__ float ulp[3][4];
  __shared__ float ul[3];
  __shared__ float Bmp[4][3][256];
  __shared__ float A2p[4][256][3];
  __shared__ float bbp[4][256];

  if (part == 0) {
    const float* ms = midsums + (size_t)(b * 256 + t) * 3;
    float se = ms[0], st = ms[1], sd = ms[2];
    float m0 = se, m1 = st - sd, m2v = sd - se;
    mid[0][t] = m0; mid[1][t] = m1; mid[2][t] = m2v;
    float s = gf[t] * rsqrtf(vfp[t] + 1e-5f);
    tl[t] = bfp[t] - mfp[t] * s;
    msc[0][t] = m0 * s; msc[1][t] = m1 * s; msc[2][t] = m2v * s;
    float s2 = g2[t] * rsqrtf(v2p[t] + 1e-5f);
    s2l[t] = s2;
    t2l[t] = b2p[t] - m2p[t] * s2;
  }
  __syncthreads();
  if (t < 3) {
    float u = 0.f;
#pragma unroll 8
    for (int c = part * 64; c < part * 64 + 64; ++c) u += mid[t][c] * tl[c];
    ulp[t][part] = u;
  }
  {
    float b0 = 0.f, b1 = 0.f, b2v = 0.f;
#pragma unroll 8
    for (int o = part * 64; o < part * 64 + 64; ++o) {
      float wfv = wfeat[o * 256 + t];          // coalesced
      b0 += msc[0][o] * wfv;
      b1 += msc[1][o] * wfv;
      b2v += msc[2][o] * wfv;
    }
    Bmp[part][0][t] = b0; Bmp[part][1][t] = b1; Bmp[part][2][t] = b2v;
  }
  __syncthreads();
  if (tid < 3) ul[tid] = ulp[tid][0] + ulp[tid][1] + ulp[tid][2] + ulp[tid][3];
  if (part == 0) {
#pragma unroll
    for (int k = 0; k < 3; ++k)
      BmW[b * 768 + k * 256 + t] =
          Bmp[0][k][t] + Bmp[1][k][t] + Bmp[2][k][t] + Bmp[3][k][t];
  }
  __syncthreads();
  if (part == 0) bias2[t] = mid[0][t] * ul[0] + mid[1][t] * ul[1] + mid[2][t] * ul[2];
  __syncthreads();
  {
    const float4* w2 = (const float4*)(wout + t * 512 + 256);  // row o=t, 2nd half
    float a0 = 0.f, a1 = 0.f, a2v = 0.f, bb = 0.f;
#pragma unroll 4
    for (int cq = part * 16; cq < part * 16 + 16; ++cq) {
      float4 wv = w2[cq];
      int c = cq * 4;
      a0 += wv.x * mid[0][c] + wv.y * mid[0][c + 1] + wv.z * mid[0][c + 2] + wv.w * mid[0][c + 3];
      a1 += wv.x * mid[1][c] + wv.y * mid[1][c + 1] + wv.z * mid[1][c + 2] + wv.w * mid[1][c + 3];
      a2v += wv.x * mid[2][c] + wv.y * mid[2][c + 1] + wv.z * mid[2][c + 2] + wv.w * mid[2][c + 3];
      bb += wv.x * bias2[c] + wv.y * bias2[c + 1] + wv.z * bias2[c + 2] + wv.w * bias2[c + 3];
    }
    A2p[part][t][0] = a0; A2p[part][t][1] = a1; A2p[part][t][2] = a2v;
    bbp[part][t] = bb;
  }
  __syncthreads();
  if (part == 0) {
#pragma unroll
    for (int k = 0; k < 3; ++k)
      A2W[(size_t)(b * 256 + t) * 3 + k] =
          A2p[0][t][k] + A2p[1][t][k] + A2p[2][t][k] + A2p[3][t][k];
    float bb = bbp[0][t] + bbp[1][t] + bbp[2][t] + bbp[3][t];
    bias_eff[b * 256 + t] = s2l[t] * bb + t2l[t];
  }
}

// ---------------------------------------------------------------------------
// K3b: W-build, 256 blocks (b x 32 o-groups of 8): W = s2*(wout1 + A2·Bm),
// bf16 store.
// ---------------------------------------------------------------------------
__global__ __launch_bounds__(256) void k_wbuild(
    const float* __restrict__ wout, const float* __restrict__ g2,
    const float* __restrict__ v2p, const float* __restrict__ BmW,
    const float* __restrict__ A2W, ushort_t* __restrict__ Wbf) {
  const int b = blockIdx.x >> 5;
  const int og = blockIdx.x & 31;   // o in [og*8, og*8+8)
  const int t = threadIdx.x;
  __shared__ float s2o[8];
  __shared__ float a2s[8][3];
  float bm0 = BmW[b * 768 + t];
  float bm1 = BmW[b * 768 + 256 + t];
  float bm2 = BmW[b * 768 + 512 + t];
  if (t < 8) {
    int o = og * 8 + t;
    s2o[t] = g2[o] * rsqrtf(v2p[o] + 1e-5f);
  }
  if (t < 24) {
    int i = t / 3, k = t % 3;
    a2s[i][k] = A2W[(size_t)(b * 256 + og * 8 + i) * 3 + k];
  }
  __syncthreads();
  ushort_t* Wb = Wbf + ((size_t)b << 16);
#pragma unroll
  for (int i = 0; i < 8; ++i) {
    int o = og * 8 + i;
    float wv = wout[o * 512 + t];            // coalesced
    float val = s2o[i] * (wv + a2s[i][0] * bm0 + a2s[i][1] * bm1 + a2s[i][2] * bm2);
    Wb[o * 256 + t] = f2bf(val);             // coalesced bf16 store
  }
}

// ---------------------------------------------------------------------------
// K4: out[b][o][n] = bias_eff[b][o] + sum_c W[b][o][c] * F[b][c][n].
// R2-proven form (best measured config): reads F fp32 (L3-hot after
// k_midsums), write-side f2bf into transposed LDS [n][c] pitch 72, B-frags
// single ds_read_b128, A-frags bf16 from global (L2-hot).
// ---------------------------------------------------------------------------
__global__ __launch_bounds__(256) void k_gemm(const float* __restrict__ f,
                                              const ushort_t* __restrict__ Wbf,
                                              const float* __restrict__ bias,
                                              float* __restrict__ out) {
  __shared__ __align__(16) ushort_t ldsT[64 * TP];   // [n=64][c=64], pitch 72
  const int b = blockIdx.x >> 8;
  const int n0 = (blockIdx.x & 255) * 64;
  const int t = threadIdx.x;
  const int wv = t >> 6;
  const int lane = t & 63;
  const int l15 = lane & 15;
  const int quad = lane >> 4;
  const int obase = wv * 64;
  const float* fb = f + ((size_t)b << 22);
  const ushort_t* Wb = Wbf + ((size_t)b << 16);
  const float* biasb = bias + (b << 8);

  const int c_loc = t >> 2;   // 0..63: channel (column in ldsT) this thread stages
  const int nb = t & 3;       // 0..3: 16-wide n-group this thread stages

  floatx4 acc[4][4];
#pragma unroll
  for (int ot = 0; ot < 4; ++ot) {
#pragma unroll
    for (int r = 0; r < 4; ++r) {
      float bv = biasb[obase + ot * 16 + quad * 4 + r];
#pragma unroll
      for (int nt = 0; nt < 4; ++nt) acc[ot][nt][r] = bv;
    }
  }

  for (int kc = 0; kc < 256; kc += 64) {
    // prefetch this tile's fp32 data while previous compute drains
    const float4* gsrc = (const float4*)(fb + (size_t)(kc + c_loc) * HW + n0);
    float4 v[4];
#pragma unroll
    for (int k = 0; k < 4; ++k) v[k] = gsrc[nb * 4 + k];
    if (kc) __syncthreads();            // protect LDS reuse
    // transposed bf16 store: column c_loc, rows nb*16 .. nb*16+15
    ushort_t* dst = ldsT + c_loc;
#pragma unroll
    for (int k = 0; k < 4; ++k) {
      int nr = nb * 16 + k * 4;
      dst[(nr + 0) * TP] = f2bf(v[k].x);
      dst[(nr + 1) * TP] = f2bf(v[k].y);
      dst[(nr + 2) * TP] = f2bf(v[k].z);
      dst[(nr + 3) * TP] = f2bf(v[k].w);
    }
    __syncthreads();
#pragma unroll
    for (int ks = 0; ks < 2; ++ks) {
      short8 a[4];
#pragma unroll
      for (int ot = 0; ot < 4; ++ot)
        a[ot] = *(const short8*)(Wb + (size_t)(obase + ot * 16 + l15) * 256 +
                                 kc + ks * 32 + quad * 8);
      short8 bfr[4];
#pragma unroll
      for (int nt = 0; nt < 4; ++nt)
        bfr[nt] = *(const short8*)(ldsT + (nt * 16 + l15) * TP + ks * 32 + quad * 8);
#pragma unroll
      for (int ot = 0; ot < 4; ++ot)
#pragma unroll
        for (int nt = 0; nt < 4; ++nt)
          acc[ot][nt] = __builtin_amdgcn_mfma_f32_16x16x32_bf16(a[ot], bfr[nt], acc[ot][nt], 0, 0, 0);
    }
  }

  float* ob = out + ((size_t)b << 22);
#pragma unroll
  for (int ot = 0; ot < 4; ++ot)
#pragma unroll
    for (int nt = 0; nt < 4; ++nt)
#pragma unroll
      for (int r = 0; r < 4; ++r)
        ob[(size_t)(obase + ot * 16 + quad * 4 + r) * HW + n0 + nt * 16 + l15] = acc[ot][nt][r];
}

// ---------------------------------------------------------------------------
extern "C" void kernel_launch(void* const* d_in, const int* in_sizes, int n_in,
                              void* d_out, int out_size, void* d_ws, size_t ws_size,
                              hipStream_t stream) {
  (void)in_sizes; (void)n_in; (void)out_size; (void)ws_size;
  const float* feature = (const float*)d_in[0];
  const float* m = (const float*)d_in[1];
  const float* w_feat = (const float*)d_in[2];
  const float* gf = (const float*)d_in[3];
  const float* bf = (const float*)d_in[4];
  const float* mf = (const float*)d_in[5];
  const float* vf = (const float*)d_in[6];
  const float* w_out = (const float*)d_in[7];
  const float* g2 = (const float*)d_in[8];
  const float* b2 = (const float*)d_in[9];
  const float* m2 = (const float*)d_in[10];
  const float* v2 = (const float*)d_in[11];
  float* out = (float*)d_out;

  char* wsb = (char*)d_ws;
  uchar_t* mk = (uchar_t*)wsb;                                // 128 KB byte mask
  float* midsums = (float*)(wsb + (1 << 20));                 // 24 KB
  float* bias_eff = (float*)(wsb + (1 << 20) + (32 << 10));   // 8 KB
  float* BmW = (float*)(wsb + (1 << 20) + (64 << 10));        // 24 KB
  float* A2W = (float*)(wsb + (1 << 20) + (128 << 10));       // 24 KB
  ushort_t* Wbf = (ushort_t*)(wsb + (2 << 20));               // 1 MB

  hipLaunchKernelGGL(k_masks, dim3(512), dim3(256), 0, stream, m, mk);
  hipLaunchKernelGGL(k_midsums, dim3(2048), dim3(256), 0, stream, feature, mk, midsums);
  hipLaunchKernelGGL(k_prep_a, dim3(8), dim3(1024), 0, stream, midsums, w_feat,
                     gf, bf, mf, vf, w_out, g2, b2, m2, v2, BmW, A2W, bias_eff);
  hipLaunchKernelGGL(k_wbuild, dim3(256), dim3(256), 0, stream, w_out, g2, v2, BmW, A2W, Wbf);
  hipLaunchKernelGGL(k_gemm, dim3(2048), dim3(256), 0, stream, feature, Wbf, bias_eff, out);
}

// Round 7
// 315.930 us; speedup vs baseline: 1.0192x; 1.0192x over previous
//
#include <hip/hip_runtime.h>

#define HW 16384
#define TP 72   // transposed bf16 LDS pitch (ushorts): 144B rows, 16B-aligned,
                // ds_read_b128 frag reads conflict-light; stores 4-way (acceptable)

typedef unsigned short ushort_t;
typedef unsigned int uint32;
typedef __attribute__((ext_vector_type(8))) short short8;
typedef __attribute__((ext_vector_type(4))) float floatx4;

__device__ __forceinline__ ushort_t f2bf(float x) {
  uint32 u = __float_as_uint(x);
  u += 0x7fffu + ((u >> 16) & 1u);
  return (ushort_t)(u >> 16);
}

// ---------------------------------------------------------------------------
// K1: binary masks. er = AND over in-bounds 4x4 window (SAME pad lo=1 hi=2,
// border does not erode/dilate, cv2 semantics); di = OR. threshold m > 0.3.
// ---------------------------------------------------------------------------
__global__ __launch_bounds__(256) void k_masks(const float* __restrict__ m,
                                               float* __restrict__ er,
                                               float* __restrict__ di) {
  int idx = blockIdx.x * 256 + threadIdx.x;   // 8*16384 total
  int b = idx >> 14;
  int p = idx & (HW - 1);
  int i = p >> 7, j = p & 127;
  const float* mb = m + (b << 14);
  float ermn = 1.f, dimx = 0.f;
  for (int di_ = -1; di_ <= 2; ++di_) {
    int ii = i + di_;
    if (ii < 0 || ii >= 128) continue;
    for (int dj = -1; dj <= 2; ++dj) {
      int jj = j + dj;
      if (jj < 0 || jj >= 128) continue;
      float z = ((double)mb[ii * 128 + jj] > 0.3) ? 1.f : 0.f;
      ermn = fminf(ermn, z);
      dimx = fmaxf(dimx, z);
    }
  }
  er[idx] = ermn;
  di[idx] = dimx;
}

// ---------------------------------------------------------------------------
// K2: per (b,c): S_er = sum er*f, S_tot = sum f, S_di = sum di*f over HW.
// One block per (b,c); direct writes (block owns its outputs, no atomics).
// er/di are 1 MB total -> L1/L2-resident broadcast reads (fmac-friendly).
// ---------------------------------------------------------------------------
__global__ __launch_bounds__(256) void k_midsums(const float* __restrict__ f,
                                                 const float* __restrict__ er,
                                                 const float* __restrict__ di,
                                                 float* __restrict__ out) {
  int b = blockIdx.x >> 8;
  int c = blockIdx.x & 255;
  const float4* f4 = (const float4*)(f + ((size_t)(b * 256 + c) << 14));
  const float4* e4 = (const float4*)(er + ((size_t)b << 14));
  const float4* d4 = (const float4*)(di + ((size_t)b << 14));
  int t = threadIdx.x;
  float se = 0.f, st = 0.f, sd = 0.f;
#pragma unroll
  for (int it = 0; it < 16; ++it) {
    int i = it * 256 + t;
    float4 x = f4[i];
    float4 e = e4[i];
    float4 dd = d4[i];
    st += (x.x + x.y) + (x.z + x.w);
    se += x.x * e.x + x.y * e.y + x.z * e.z + x.w * e.w;
    sd += x.x * dd.x + x.y * dd.y + x.z * dd.z + x.w * dd.w;
  }
  __shared__ float red[3][4];
  for (int off = 32; off; off >>= 1) {
    se += __shfl_down(se, off);
    st += __shfl_down(st, off);
    sd += __shfl_down(sd, off);
  }
  int wave = t >> 6;
  if ((t & 63) == 0) { red[0][wave] = se; red[1][wave] = st; red[2][wave] = sd; }
  __syncthreads();
  if (t == 0) {
    se = red[0][0] + red[0][1] + red[0][2] + red[0][3];
    st = red[1][0] + red[1][1] + red[1][2] + red[1][3];
    sd = red[2][0] + red[2][1] + red[2][2] + red[2][3];
    float* o = out + (size_t)(b * 256 + c) * 3;
    o[0] = se; o[1] = st; o[2] = sd;
  }
}

// ---------------------------------------------------------------------------
// K3a: per-batch small algebra, 1024 threads (4-way split of every 256-deep
// reduction loop + LDS reduce) -> Bm[3][256], A2[256][3], bias_eff.
// ---------------------------------------------------------------------------
__global__ __launch_bounds__(1024) void k_prep_a(
    const float* __restrict__ midsums, const float* __restrict__ wfeat,
    const float* __restrict__ gf, const float* __restrict__ bfp,
    const float* __restrict__ mfp, const float* __restrict__ vfp,
    const float* __restrict__ wout, const float* __restrict__ g2,
    const float* __restrict__ b2p, const float* __restrict__ m2p,
    const float* __restrict__ v2p, float* __restrict__ BmW,
    float* __restrict__ A2W, float* __restrict__ bias_eff) {
  const int b = blockIdx.x;
  const int tid = threadIdx.x;
  const int t = tid & 255;
  const int part = tid >> 8;      // 0..3
  __shared__ float mid[3][256];
  __shared__ float msc[3][256];
  __shared__ float tl[256];
  __shared__ float s2l[256], t2l[256];
  __shared__ float bias2[256];
  __shared__ float ulp[3][4];
  __shared__ float ul[3];
  __shared__ float Bmp[4][3][256];
  __shared__ float A2p[4][256][3];
  __shared__ float bbp[4][256];

  if (part == 0) {
    const float* ms = midsums + (size_t)(b * 256 + t) * 3;
    float se = ms[0], st = ms[1], sd = ms[2];
    float m0 = se, m1 = st - sd, m2v = sd - se;
    mid[0][t] = m0; mid[1][t] = m1; mid[2][t] = m2v;
    float s = gf[t] * rsqrtf(vfp[t] + 1e-5f);
    tl[t] = bfp[t] - mfp[t] * s;
    msc[0][t] = m0 * s; msc[1][t] = m1 * s; msc[2][t] = m2v * s;
    float s2 = g2[t] * rsqrtf(v2p[t] + 1e-5f);
    s2l[t] = s2;
    t2l[t] = b2p[t] - m2p[t] * s2;
  }
  __syncthreads();
  if (t < 3) {
    float u = 0.f;
#pragma unroll 8
    for (int c = part * 64; c < part * 64 + 64; ++c) u += mid[t][c] * tl[c];
    ulp[t][part] = u;
  }
  {
    float b0 = 0.f, b1 = 0.f, b2v = 0.f;
#pragma unroll 8
    for (int o = part * 64; o < part * 64 + 64; ++o) {
      float wfv = wfeat[o * 256 + t];          // coalesced
      b0 += msc[0][o] * wfv;
      b1 += msc[1][o] * wfv;
      b2v += msc[2][o] * wfv;
    }
    Bmp[part][0][t] = b0; Bmp[part][1][t] = b1; Bmp[part][2][t] = b2v;
  }
  __syncthreads();
  if (tid < 3) ul[tid] = ulp[tid][0] + ulp[tid][1] + ulp[tid][2] + ulp[tid][3];
  if (part == 0) {
#pragma unroll
    for (int k = 0; k < 3; ++k)
      BmW[b * 768 + k * 256 + t] =
          Bmp[0][k][t] + Bmp[1][k][t] + Bmp[2][k][t] + Bmp[3][k][t];
  }
  __syncthreads();
  if (part == 0) bias2[t] = mid[0][t] * ul[0] + mid[1][t] * ul[1] + mid[2][t] * ul[2];
  __syncthreads();
  {
    const float4* w2 = (const float4*)(wout + t * 512 + 256);  // row o=t, 2nd half
    float a0 = 0.f, a1 = 0.f, a2v = 0.f, bb = 0.f;
#pragma unroll 4
    for (int cq = part * 16; cq < part * 16 + 16; ++cq) {
      float4 wv = w2[cq];
      int c = cq * 4;
      a0 += wv.x * mid[0][c] + wv.y * mid[0][c + 1] + wv.z * mid[0][c + 2] + wv.w * mid[0][c + 3];
      a1 += wv.x * mid[1][c] + wv.y * mid[1][c + 1] + wv.z * mid[1][c + 2] + wv.w * mid[1][c + 3];
      a2v += wv.x * mid[2][c] + wv.y * mid[2][c + 1] + wv.z * mid[2][c + 2] + wv.w * mid[2][c + 3];
      bb += wv.x * bias2[c] + wv.y * bias2[c + 1] + wv.z * bias2[c + 2] + wv.w * bias2[c + 3];
    }
    A2p[part][t][0] = a0; A2p[part][t][1] = a1; A2p[part][t][2] = a2v;
    bbp[part][t] = bb;
  }
  __syncthreads();
  if (part == 0) {
#pragma unroll
    for (int k = 0; k < 3; ++k)
      A2W[(size_t)(b * 256 + t) * 3 + k] =
          A2p[0][t][k] + A2p[1][t][k] + A2p[2][t][k] + A2p[3][t][k];
    float bb = bbp[0][t] + bbp[1][t] + bbp[2][t] + bbp[3][t];
    bias_eff[b * 256 + t] = s2l[t] * bb + t2l[t];
  }
}

// ---------------------------------------------------------------------------
// K3b: W-build, 256 blocks (b x 32 o-groups of 8): W = s2*(wout1 + A2·Bm),
// bf16 store.
// ---------------------------------------------------------------------------
__global__ __launch_bounds__(256) void k_wbuild(
    const float* __restrict__ wout, const float* __restrict__ g2,
    const float* __restrict__ v2p, const float* __restrict__ BmW,
    const float* __restrict__ A2W, ushort_t* __restrict__ Wbf) {
  const int b = blockIdx.x >> 5;
  const int og = blockIdx.x & 31;   // o in [og*8, og*8+8)
  const int t = threadIdx.x;
  __shared__ float s2o[8];
  __shared__ float a2s[8][3];
  float bm0 = BmW[b * 768 + t];
  float bm1 = BmW[b * 768 + 256 + t];
  float bm2 = BmW[b * 768 + 512 + t];
  if (t < 8) {
    int o = og * 8 + t;
    s2o[t] = g2[o] * rsqrtf(v2p[o] + 1e-5f);
  }
  if (t < 24) {
    int i = t / 3, k = t % 3;
    a2s[i][k] = A2W[(size_t)(b * 256 + og * 8 + i) * 3 + k];
  }
  __syncthreads();
  ushort_t* Wb = Wbf + ((size_t)b << 16);
#pragma unroll
  for (int i = 0; i < 8; ++i) {
    int o = og * 8 + i;
    float wv = wout[o * 512 + t];            // coalesced
    float val = s2o[i] * (wv + a2s[i][0] * bm0 + a2s[i][1] * bm1 + a2s[i][2] * bm2);
    Wb[o * 256 + t] = f2bf(val);             // coalesced bf16 store
  }
}

// ---------------------------------------------------------------------------
// K4: out[b][o][n] = bias_eff[b][o] + sum_c W[b][o][c] * F[b][c][n].
// Best-measured form (R2): reads F fp32 (L3-hot after k_midsums), write-side
// f2bf into transposed LDS [n][c] pitch 72, B-frags single ds_read_b128,
// A-frags bf16 from global (L2-hot).
// ---------------------------------------------------------------------------
__global__ __launch_bounds__(256) void k_gemm(const float* __restrict__ f,
                                              const ushort_t* __restrict__ Wbf,
                                              const float* __restrict__ bias,
                                              float* __restrict__ out) {
  __shared__ __align__(16) ushort_t ldsT[64 * TP];   // [n=64][c=64], pitch 72
  const int b = blockIdx.x >> 8;
  const int n0 = (blockIdx.x & 255) * 64;
  const int t = threadIdx.x;
  const int wv = t >> 6;
  const int lane = t & 63;
  const int l15 = lane & 15;
  const int quad = lane >> 4;
  const int obase = wv * 64;
  const float* fb = f + ((size_t)b << 22);
  const ushort_t* Wb = Wbf + ((size_t)b << 16);
  const float* biasb = bias + (b << 8);

  const int c_loc = t >> 2;   // 0..63: channel (column in ldsT) this thread stages
  const int nb = t & 3;       // 0..3: 16-wide n-group this thread stages

  floatx4 acc[4][4];
#pragma unroll
  for (int ot = 0; ot < 4; ++ot) {
#pragma unroll
    for (int r = 0; r < 4; ++r) {
      float bv = biasb[obase + ot * 16 + quad * 4 + r];
#pragma unroll
      for (int nt = 0; nt < 4; ++nt) acc[ot][nt][r] = bv;
    }
  }

  for (int kc = 0; kc < 256; kc += 64) {
    // prefetch this tile's fp32 data while previous compute drains
    const float4* gsrc = (const float4*)(fb + (size_t)(kc + c_loc) * HW + n0);
    float4 v[4];
#pragma unroll
    for (int k = 0; k < 4; ++k) v[k] = gsrc[nb * 4 + k];
    if (kc) __syncthreads();            // protect LDS reuse
    // transposed bf16 store: column c_loc, rows nb*16 .. nb*16+15
    ushort_t* dst = ldsT + c_loc;
#pragma unroll
    for (int k = 0; k < 4; ++k) {
      int nr = nb * 16 + k * 4;
      dst[(nr + 0) * TP] = f2bf(v[k].x);
      dst[(nr + 1) * TP] = f2bf(v[k].y);
      dst[(nr + 2) * TP] = f2bf(v[k].z);
      dst[(nr + 3) * TP] = f2bf(v[k].w);
    }
    __syncthreads();
#pragma unroll
    for (int ks = 0; ks < 2; ++ks) {
      short8 a[4];
#pragma unroll
      for (int ot = 0; ot < 4; ++ot)
        a[ot] = *(const short8*)(Wb + (size_t)(obase + ot * 16 + l15) * 256 +
                                 kc + ks * 32 + quad * 8);
      short8 bfr[4];
#pragma unroll
      for (int nt = 0; nt < 4; ++nt)
        bfr[nt] = *(const short8*)(ldsT + (nt * 16 + l15) * TP + ks * 32 + quad * 8);
#pragma unroll
      for (int ot = 0; ot < 4; ++ot)
#pragma unroll
        for (int nt = 0; nt < 4; ++nt)
          acc[ot][nt] = __builtin_amdgcn_mfma_f32_16x16x32_bf16(a[ot], bfr[nt], acc[ot][nt], 0, 0, 0);
    }
  }

  float* ob = out + ((size_t)b << 22);
#pragma unroll
  for (int ot = 0; ot < 4; ++ot)
#pragma unroll
    for (int nt = 0; nt < 4; ++nt)
#pragma unroll
      for (int r = 0; r < 4; ++r)
        ob[(size_t)(obase + ot * 16 + quad * 4 + r) * HW + n0 + nt * 16 + l15] = acc[ot][nt][r];
}

// ---------------------------------------------------------------------------
extern "C" void kernel_launch(void* const* d_in, const int* in_sizes, int n_in,
                              void* d_out, int out_size, void* d_ws, size_t ws_size,
                              hipStream_t stream) {
  (void)in_sizes; (void)n_in; (void)out_size; (void)ws_size;
  const float* feature = (const float*)d_in[0];
  const float* m = (const float*)d_in[1];
  const float* w_feat = (const float*)d_in[2];
  const float* gf = (const float*)d_in[3];
  const float* bf = (const float*)d_in[4];
  const float* mf = (const float*)d_in[5];
  const float* vf = (const float*)d_in[6];
  const float* w_out = (const float*)d_in[7];
  const float* g2 = (const float*)d_in[8];
  const float* b2 = (const float*)d_in[9];
  const float* m2 = (const float*)d_in[10];
  const float* v2 = (const float*)d_in[11];
  float* out = (float*)d_out;

  char* wsb = (char*)d_ws;
  float* er = (float*)wsb;                                    // 512 KB
  float* di = (float*)(wsb + (512 << 10));                    // 512 KB
  float* midsums = (float*)(wsb + (1 << 20));                 // 24 KB
  float* bias_eff = (float*)(wsb + (1 << 20) + (32 << 10));   // 8 KB
  float* BmW = (float*)(wsb + (1 << 20) + (64 << 10));        // 24 KB
  float* A2W = (float*)(wsb + (1 << 20) + (128 << 10));       // 24 KB
  ushort_t* Wbf = (ushort_t*)(wsb + (2 << 20));               // 1 MB

  hipLaunchKernelGGL(k_masks, dim3(512), dim3(256), 0, stream, m, er, di);
  hipLaunchKernelGGL(k_midsums, dim3(2048), dim3(256), 0, stream, feature, er, di, midsums);
  hipLaunchKernelGGL(k_prep_a, dim3(8), dim3(1024), 0, stream, midsums, w_feat,
                     gf, bf, mf, vf, w_out, g2, b2, m2, v2, BmW, A2W, bias_eff);
  hipLaunchKernelGGL(k_wbuild, dim3(256), dim3(256), 0, stream, w_out, g2, v2, BmW, A2W, Wbf);
  hipLaunchKernelGGL(k_gemm, dim3(2048), dim3(256), 0, stream, feature, Wbf, bias_eff, out);
}